// Round 13
// baseline (180.582 us; speedup 1.0000x reference)
//
#include <hip/hip_runtime.h>
#include <hip/hip_bf16.h>

#define Tcnt 32768      // B*S
#define Gn   2
#define Vn   320
#define Dn   128
#define DIMK 512
#define GV   640        // G*V
#define RB   64         // rows per fused block
#define NCAND 8

typedef __attribute__((ext_vector_type(8))) short bf16x8;
typedef __attribute__((ext_vector_type(8))) ushort u16x8;
typedef __attribute__((ext_vector_type(4))) float f32x4;

__device__ inline ushort f2bf(float x) {
    unsigned u = __float_as_uint(x);
    return (ushort)((u + 0x7fffu + ((u >> 16) & 1u)) >> 16);   // RNE
}
__device__ inline ushort nbf(float x) {                        // native RNE cvt
    __hip_bfloat16 h = __float2bfloat16(x);
    return *reinterpret_cast<ushort*>(&h);
}
__device__ inline bf16x8 cvt8(float4 a, float4 b) {
    u16x8 o;
    o[0]=nbf(a.x); o[1]=nbf(a.y); o[2]=nbf(a.z); o[3]=nbf(a.w);
    o[4]=nbf(b.x); o[5]=nbf(b.y); o[6]=nbf(b.z); o[7]=nbf(b.w);
    return (bf16x8)o;
}

#define AS1(p) ((const __attribute__((address_space(1))) void*)(p))
#define AS3(p) ((__attribute__((address_space(3))) void*)(p))

// ---------------- prep: W [512,640] fp32 -> Wt [640,512] bf16 (transposed) ----------
__global__ __launch_bounds__(256) void prep_wt(
    const float* __restrict__ W, ushort* __restrict__ Wt)
{
    __shared__ ushort Ls[64][72];
    int t = blockIdx.x;                     // 0..79
    int n0 = (t % 10) * 64, k0 = (t / 10) * 64;
    int ln = threadIdx.x & 63, kq = threadIdx.x >> 6;
    #pragma unroll
    for (int kk = 0; kk < 16; ++kk) {
        int k = kq * 16 + kk;
        Ls[k][ln] = f2bf(W[(size_t)(k0 + k) * GV + n0 + ln]);
    }
    __syncthreads();
    #pragma unroll
    for (int nn = 0; nn < 16; ++nn) {
        int n = kq * 16 + nn;
        Wt[(size_t)(n0 + n) * DIMK + k0 + ln] = Ls[ln][n];
    }
}

// ------- fused: GEMM(64x320) A-direct + Bs-dbuf(gll) + softmax/argmax/fixup/gather --
// 512 thr / 8 waves; wave-tile 16x160; LDS = union(Bs 40K, ep 9K) -> 3 blocks/CU.
__global__ __launch_bounds__(512, 6) void fused_vq_kernel(
    const float*  __restrict__ hs,    // [T, 512] fp32
    const ushort* __restrict__ Wt,    // [640, 512] bf16 transposed
    const float*  __restrict__ W,     // [512, 640] fp32 (fixup only)
    const float*  __restrict__ bias,  // [640]
    const float*  __restrict__ gum,   // [T*G, 320]
    const float*  __restrict__ cv,    // [640, 128]
    float* __restrict__ out,          // [T, 256]
    float* __restrict__ dist)         // [T*G, 320]
{
    union SMem {
        ushort Bs[2][Vn * 32];        // 40 KB (dbuf, gll-staged, chunk-swizzled)
        struct {
            float4 part[RB][2];       // {mxl, sum, mxs, idx} per col-half
            int    cnt[RB];
            int    col[RB][NCAND];
            float  sc[RB][NCAND];
            float  gmv[RB][NCAND];
            int    bidx[RB];
            float  mxs[RB];
        } ep;                          // ~9 KB
    };
    __shared__ SMem U;

    const int tid = threadIdx.x, w = tid >> 6, lane = tid & 63;
    const int Q = lane >> 4, c16 = lane & 15;
    const int wm = (w >> 1) * 16, wn = (w & 1) * 160, half = w & 1;

    const int bid = blockIdx.x;
    const int swz = (bid & 7) * 128 + (bid >> 3);   // XCD chunking (1024 % 8 == 0)
    const int g = swz & 1;                          // (t,g0),(t,g1) adjacent on same XCD
    const size_t t0 = (size_t)(swz >> 1) * RB;

    const ushort* wtg = Wt + (size_t)g * Vn * DIMK;
    const float*  abase = hs + (t0 + wm + c16) * DIMK + Q * 8;   // A direct per-lane

    auto stageB = [&](int buf, int k0) {
        #pragma unroll
        for (int i2 = 0; i2 < 2; ++i2) {
            int s = i2 * 512 + tid;
            int n = s >> 2, pq = s & 3, lqq = pq ^ ((n >> 1) & 3);
            __builtin_amdgcn_global_load_lds(
                AS1(wtg + (size_t)n * DIMK + k0 + lqq * 8),
                AS3(&U.Bs[buf][s * 8]), 16, 0, 0);
        }
        if (w < 4) {
            int s = 1024 + tid;
            int n = s >> 2, pq = s & 3, lqq = pq ^ ((n >> 1) & 3);
            __builtin_amdgcn_global_load_lds(
                AS1(wtg + (size_t)n * DIMK + k0 + lqq * 8),
                AS3(&U.Bs[buf][s * 8]), 16, 0, 0);
        }
    };

    // ---- prologue: stage step 0; load A step 0 ----
    stageB(0, 0);
    float4 aC0 = *(const float4*)(abase);
    float4 aC1 = *(const float4*)(abase + 4);
    float4 aN0, aN1;
    __syncthreads();                 // Bs[0] staged (vmcnt drain), A0 in regs

    f32x4 acc[10];
    #pragma unroll
    for (int j = 0; j < 10; ++j) acc[j] = (f32x4){0.f, 0.f, 0.f, 0.f};

    // ---- K loop: 16 steps BK=32, Bs dbuf (gll), A-direct depth-1 prefetch ----
    #pragma unroll
    for (int ks = 0; ks < 16; ++ks) {
        if (ks < 15) {
            stageB((ks + 1) & 1, (ks + 1) * 32);
            aN0 = *(const float4*)(abase + (ks + 1) * 32);
            aN1 = *(const float4*)(abase + (ks + 1) * 32 + 4);
        }
        bf16x8 af = cvt8(aC0, aC1);
        const ushort* Bb = U.Bs[ks & 1];
        #pragma unroll
        for (int j = 0; j < 10; ++j) {
            int n = wn + j * 16 + c16;
            bf16x8 bv = *(const bf16x8*)&Bb[(n * 4 + (Q ^ ((n >> 1) & 3))) * 8];
            acc[j] = __builtin_amdgcn_mfma_f32_16x16x32_bf16(af, bv, acc[j], 0, 0, 0);
        }
        __syncthreads();             // next tile staged + all reads of cur done
        aC0 = aN0; aC1 = aN1;
    }

    // ---- bias ----
    #pragma unroll
    for (int j = 0; j < 10; ++j) {
        float bb = bias[g * Vn + wn + j * 16 + c16];
        acc[j][0] += bb; acc[j][1] += bb; acc[j][2] += bb; acc[j][3] += bb;
    }

    // Bs dead; switch union to ep after init+barrier
    if (tid < RB) U.ep.cnt[tid] = 0;
    __syncthreads();

    const float MARGIN = 0.0625f;

    // ---- phase 1: per-row half-stats + candidate pool ----
    #pragma unroll
    for (int qr = 0; qr < 4; ++qr) {
        int row = wm + Q * 4 + qr;                 // local row (C/D layout)
        size_t r2 = (t0 + row) * 2 + g;
        const float* gr = gum + r2 * Vn + wn;
        float sv[10];
        float mxl = -1e30f, mxs = -1e30f; int bi = 0;
        #pragma unroll
        for (int j = 0; j < 10; ++j) {
            float lg = acc[j][qr];
            float gu = gr[j * 16 + c16];
            float s = lg + gu; sv[j] = s;
            mxl = fmaxf(mxl, lg);
            if (s > mxs) { mxs = s; bi = wn + j * 16 + c16; }
        }
        #pragma unroll
        for (int off = 1; off < 16; off <<= 1) {
            mxl = fmaxf(mxl, __shfl_xor(mxl, off));
            float os = __shfl_xor(mxs, off); int ob = __shfl_xor(bi, off);
            if (os > mxs || (os == mxs && ob < bi)) { mxs = os; bi = ob; }
        }
        float sum = 0.f;
        #pragma unroll
        for (int j = 0; j < 10; ++j) sum += __expf(acc[j][qr] - mxl);
        #pragma unroll
        for (int off = 1; off < 16; off <<= 1) sum += __shfl_xor(sum, off);

        float thr = mxs - MARGIN;
        #pragma unroll
        for (int j = 0; j < 10; ++j) {
            if (sv[j] >= thr) {
                int pos = atomicAdd(&U.ep.cnt[row], 1);
                if (pos < NCAND) {
                    U.ep.col[row][pos] = wn + j * 16 + c16;
                    U.ep.sc[row][pos]  = sv[j];
                    U.ep.gmv[row][pos] = sv[j] - acc[j][qr];
                }
            }
        }
        if (c16 == 0)
            U.ep.part[row][half] = (float4){mxl, sum, mxs, __int_as_float(bi)};
    }
    __syncthreads();

    // ---- phase 2: combine halves, write dist, final approx argmax ----
    #pragma unroll
    for (int qr = 0; qr < 4; ++qr) {
        int row = wm + Q * 4 + qr;
        size_t r2 = (t0 + row) * 2 + g;
        float4 mine = U.ep.part[row][half];
        float4 oth  = U.ep.part[row][half ^ 1];
        float mxl_f = fmaxf(mine.x, oth.x);
        float sum_f = mine.y * __expf(mine.x - mxl_f) + oth.y * __expf(oth.x - mxl_f);
        float inv = 1.0f / sum_f;
        float* dr = dist + r2 * Vn + wn;
        #pragma unroll
        for (int j = 0; j < 10; ++j)
            dr[j * 16 + c16] = __expf(acc[j][qr] - mxl_f) * inv;
        if (half == 0 && c16 == 0) {
            float ms = mine.z; int mi = __float_as_int(mine.w);
            float os = oth.z;  int oi = __float_as_int(oth.w);
            if (os > ms || (os == ms && oi < mi)) { ms = os; mi = oi; }
            U.ep.mxs[row] = ms; U.ep.bidx[row] = mi;
        }
    }
    __syncthreads();

    // ---- fixup: exact fp32 recompute for near-tie rows (8 units/wave) ----
    for (int ui = 0; ui < 8; ++ui) {
        int u = w * 8 + ui;
        int c = U.ep.cnt[u]; if (c > NCAND) c = NCAND;
        float thr = U.ep.mxs[u] - MARGIN;
        int nf = 0;
        for (int j = 0; j < c; ++j) nf += (U.ep.sc[u][j] >= thr) ? 1 : 0;
        if (nf > 1) {
            size_t t = t0 + u;
            const float* hr = hs + t * DIMK;
            float4 h0 = *(const float4*)(hr + lane * 8);
            float4 h1 = *(const float4*)(hr + lane * 8 + 4);
            float hv[8] = {h0.x, h0.y, h0.z, h0.w, h1.x, h1.y, h1.z, h1.w};
            float best = -1e30f; int bv2 = 1 << 30;
            for (int j = 0; j < c; ++j) {
                if (U.ep.sc[u][j] < thr) continue;
                int v = U.ep.col[u][j];
                int gcol = g * Vn + v;
                const float* wc = W + gcol;
                float p = 0.f;
                #pragma unroll
                for (int i = 0; i < 8; ++i)
                    p = fmaf(hv[i], wc[(size_t)(lane * 8 + i) * GV], p);
                #pragma unroll
                for (int off = 1; off < 64; off <<= 1) p += __shfl_xor(p, off);
                float se = p + bias[gcol] + U.ep.gmv[u][j];
                if (se > best || (se == best && v < bv2)) { best = se; bv2 = v; }
            }
            if (lane == 0) U.ep.bidx[u] = bv2;
        }
    }
    __syncthreads();

    // ---- gather codevectors -> out ----
    for (int ui = 0; ui < 8; ++ui) {
        int u = w * 8 + ui;
        size_t t = t0 + u;
        int b = U.ep.bidx[u];
        const float2* cvr = (const float2*)(cv + ((size_t)(g * Vn + b)) * Dn);
        float2 val = cvr[lane];
        *(float2*)(out + t * (Gn * Dn) + g * Dn + lane * 2) = val;
    }
}

extern "C" void kernel_launch(void* const* d_in, const int* in_sizes, int n_in,
                              void* d_out, int out_size, void* d_ws, size_t ws_size,
                              hipStream_t stream) {
    const float* hs  = (const float*)d_in[0];  // [8,4096,512]
    const float* W   = (const float*)d_in[1];  // [512,640]
    const float* b   = (const float*)d_in[2];  // [640]
    const float* cv  = (const float*)d_in[3];  // [640,128]
    const float* gum = (const float*)d_in[4];  // [65536,320]

    float* out  = (float*)d_out;                      // [32768, 256]
    float* dist = out + (size_t)Tcnt * (Gn * Dn);     // [65536, 320]
    ushort* Wt  = (ushort*)d_ws;                      // [640, 512] bf16 = 640 KB

    prep_wt<<<80, 256, 0, stream>>>(W, Wt);
    fused_vq_kernel<<<(Tcnt / RB) * Gn, 512, 0, stream>>>(hs, Wt, W, b, gum, cv, out, dist);
}

// Round 14
// 110.077 us; speedup vs baseline: 1.6405x; 1.6405x over previous
//
#include <hip/hip_runtime.h>
#include <hip/hip_bf16.h>

#define Tcnt 32768      // B*S
#define Gn   2
#define Vn   320
#define Dn   128
#define DIMK 512
#define GV   640        // G*V
#define RB   64         // rows per fused block
#define NCAND 8

typedef __attribute__((ext_vector_type(8))) short bf16x8;
typedef __attribute__((ext_vector_type(8))) ushort u16x8;
typedef __attribute__((ext_vector_type(4))) float f32x4;

__device__ inline ushort f2bf(float x) {
    unsigned u = __float_as_uint(x);
    return (ushort)((u + 0x7fffu + ((u >> 16) & 1u)) >> 16);   // RNE
}
__device__ inline ushort nbf(float x) {                        // native RNE cvt
    __hip_bfloat16 h = __float2bfloat16(x);
    return *reinterpret_cast<ushort*>(&h);
}
__device__ inline bf16x8 cvt8(float4 a, float4 b) {
    u16x8 o;
    o[0]=nbf(a.x); o[1]=nbf(a.y); o[2]=nbf(a.z); o[3]=nbf(a.w);
    o[4]=nbf(b.x); o[5]=nbf(b.y); o[6]=nbf(b.z); o[7]=nbf(b.w);
    return (bf16x8)o;
}

#define AS1(p) ((const __attribute__((address_space(1))) void*)(p))
#define AS3(p) ((__attribute__((address_space(3))) void*)(p))

// ---------------- prep: W [512,640] fp32 -> Wt [640,512] bf16 (transposed) ----------
__global__ __launch_bounds__(256) void prep_wt(
    const float* __restrict__ W, ushort* __restrict__ Wt)
{
    __shared__ ushort Ls[64][72];
    int t = blockIdx.x;                     // 0..79
    int n0 = (t % 10) * 64, k0 = (t / 10) * 64;
    int ln = threadIdx.x & 63, kq = threadIdx.x >> 6;
    #pragma unroll
    for (int kk = 0; kk < 16; ++kk) {
        int k = kq * 16 + kk;
        Ls[k][ln] = f2bf(W[(size_t)(k0 + k) * GV + n0 + ln]);
    }
    __syncthreads();
    #pragma unroll
    for (int nn = 0; nn < 16; ++nn) {
        int n = kq * 16 + nn;
        Wt[(size_t)(n0 + n) * DIMK + k0 + ln] = Ls[ln][n];
    }
}

// ------- fused: GEMM(64x320) A-direct + Bs-dbuf(gll) + softmax/argmax/fixup/gather --
// 512 thr / 8 waves; wave-tile 16x160; LDS = union(Bs 40K, ep 9K).
// __launch_bounds__(512,4): VGPR cap 128 -> ~80 alloc, no spill; HW settles ~3 blk/CU.
__global__ __launch_bounds__(512, 4) void fused_vq_kernel(
    const float*  __restrict__ hs,    // [T, 512] fp32
    const ushort* __restrict__ Wt,    // [640, 512] bf16 transposed
    const float*  __restrict__ W,     // [512, 640] fp32 (fixup only)
    const float*  __restrict__ bias,  // [640]
    const float*  __restrict__ gum,   // [T*G, 320]
    const float*  __restrict__ cv,    // [640, 128]
    float* __restrict__ out,          // [T, 256]
    float* __restrict__ dist)         // [T*G, 320]
{
    union SMem {
        ushort Bs[2][Vn * 32];        // 40 KB (dbuf, gll-staged, chunk-swizzled)
        struct {
            float4 part[RB][2];       // {mxl, sum, mxs, idx} per col-half
            int    cnt[RB];
            int    col[RB][NCAND];
            float  sc[RB][NCAND];
            float  gmv[RB][NCAND];
            int    bidx[RB];
            float  mxs[RB];
        } ep;                          // ~9 KB
    };
    __shared__ SMem U;

    const int tid = threadIdx.x, w = tid >> 6, lane = tid & 63;
    const int Q = lane >> 4, c16 = lane & 15;
    const int wm = (w >> 1) * 16, wn = (w & 1) * 160, half = w & 1;

    const int bid = blockIdx.x;
    const int swz = (bid & 7) * 128 + (bid >> 3);   // XCD chunking (1024 % 8 == 0)
    const int g = swz & 1;                          // (t,g0),(t,g1) adjacent on same XCD
    const size_t t0 = (size_t)(swz >> 1) * RB;

    const ushort* wtg = Wt + (size_t)g * Vn * DIMK;
    const float*  abase = hs + (t0 + wm + c16) * DIMK + Q * 8;   // A direct per-lane

    auto stageB = [&](int buf, int k0) {
        #pragma unroll
        for (int i2 = 0; i2 < 2; ++i2) {
            int s = i2 * 512 + tid;
            int n = s >> 2, pq = s & 3, lqq = pq ^ ((n >> 1) & 3);
            __builtin_amdgcn_global_load_lds(
                AS1(wtg + (size_t)n * DIMK + k0 + lqq * 8),
                AS3(&U.Bs[buf][s * 8]), 16, 0, 0);
        }
        if (w < 4) {
            int s = 1024 + tid;
            int n = s >> 2, pq = s & 3, lqq = pq ^ ((n >> 1) & 3);
            __builtin_amdgcn_global_load_lds(
                AS1(wtg + (size_t)n * DIMK + k0 + lqq * 8),
                AS3(&U.Bs[buf][s * 8]), 16, 0, 0);
        }
    };

    // ---- prologue: stage step 0; load A step 0 ----
    stageB(0, 0);
    float4 aC0 = *(const float4*)(abase);
    float4 aC1 = *(const float4*)(abase + 4);
    float4 aN0, aN1;
    __syncthreads();                 // Bs[0] staged (vmcnt drain), A0 in regs

    f32x4 acc[10];
    #pragma unroll
    for (int j = 0; j < 10; ++j) acc[j] = (f32x4){0.f, 0.f, 0.f, 0.f};

    // ---- K loop: 16 steps BK=32, Bs dbuf (gll), A-direct depth-1 prefetch ----
    #pragma unroll
    for (int ks = 0; ks < 16; ++ks) {
        if (ks < 15) {
            stageB((ks + 1) & 1, (ks + 1) * 32);
            aN0 = *(const float4*)(abase + (ks + 1) * 32);
            aN1 = *(const float4*)(abase + (ks + 1) * 32 + 4);
        }
        bf16x8 af = cvt8(aC0, aC1);
        const ushort* Bb = U.Bs[ks & 1];
        #pragma unroll
        for (int j = 0; j < 10; ++j) {
            int n = wn + j * 16 + c16;
            bf16x8 bv = *(const bf16x8*)&Bb[(n * 4 + (Q ^ ((n >> 1) & 3))) * 8];
            acc[j] = __builtin_amdgcn_mfma_f32_16x16x32_bf16(af, bv, acc[j], 0, 0, 0);
        }
        __syncthreads();             // next tile staged + all reads of cur done
        aC0 = aN0; aC1 = aN1;
    }

    // ---- bias ----
    #pragma unroll
    for (int j = 0; j < 10; ++j) {
        float bb = bias[g * Vn + wn + j * 16 + c16];
        acc[j][0] += bb; acc[j][1] += bb; acc[j][2] += bb; acc[j][3] += bb;
    }

    // Bs dead; switch union to ep after init+barrier
    if (tid < RB) U.ep.cnt[tid] = 0;
    __syncthreads();

    const float MARGIN = 0.0625f;

    // ---- phase 1: per-row half-stats + candidate pool ----
    #pragma unroll
    for (int qr = 0; qr < 4; ++qr) {
        int row = wm + Q * 4 + qr;                 // local row (C/D layout)
        size_t r2 = (t0 + row) * 2 + g;
        const float* gr = gum + r2 * Vn + wn;
        float sv[10];
        float mxl = -1e30f, mxs = -1e30f; int bi = 0;
        #pragma unroll
        for (int j = 0; j < 10; ++j) {
            float lg = acc[j][qr];
            float gu = gr[j * 16 + c16];
            float s = lg + gu; sv[j] = s;
            mxl = fmaxf(mxl, lg);
            if (s > mxs) { mxs = s; bi = wn + j * 16 + c16; }
        }
        #pragma unroll
        for (int off = 1; off < 16; off <<= 1) {
            mxl = fmaxf(mxl, __shfl_xor(mxl, off));
            float os = __shfl_xor(mxs, off); int ob = __shfl_xor(bi, off);
            if (os > mxs || (os == mxs && ob < bi)) { mxs = os; bi = ob; }
        }
        float sum = 0.f;
        #pragma unroll
        for (int j = 0; j < 10; ++j) sum += __expf(acc[j][qr] - mxl);
        #pragma unroll
        for (int off = 1; off < 16; off <<= 1) sum += __shfl_xor(sum, off);

        float thr = mxs - MARGIN;
        #pragma unroll
        for (int j = 0; j < 10; ++j) {
            if (sv[j] >= thr) {
                int pos = atomicAdd(&U.ep.cnt[row], 1);
                if (pos < NCAND) {
                    U.ep.col[row][pos] = wn + j * 16 + c16;
                    U.ep.sc[row][pos]  = sv[j];
                    U.ep.gmv[row][pos] = sv[j] - acc[j][qr];
                }
            }
        }
        if (c16 == 0)
            U.ep.part[row][half] = (float4){mxl, sum, mxs, __int_as_float(bi)};
    }
    __syncthreads();

    // ---- phase 2: combine halves, write dist, final approx argmax ----
    #pragma unroll
    for (int qr = 0; qr < 4; ++qr) {
        int row = wm + Q * 4 + qr;
        size_t r2 = (t0 + row) * 2 + g;
        float4 mine = U.ep.part[row][half];
        float4 oth  = U.ep.part[row][half ^ 1];
        float mxl_f = fmaxf(mine.x, oth.x);
        float sum_f = mine.y * __expf(mine.x - mxl_f) + oth.y * __expf(oth.x - mxl_f);
        float inv = 1.0f / sum_f;
        float* dr = dist + r2 * Vn + wn;
        #pragma unroll
        for (int j = 0; j < 10; ++j)
            dr[j * 16 + c16] = __expf(acc[j][qr] - mxl_f) * inv;
        if (half == 0 && c16 == 0) {
            float ms = mine.z; int mi = __float_as_int(mine.w);
            float os = oth.z;  int oi = __float_as_int(oth.w);
            if (os > ms || (os == ms && oi < mi)) { ms = os; mi = oi; }
            U.ep.mxs[row] = ms; U.ep.bidx[row] = mi;
        }
    }
    __syncthreads();

    // ---- fixup: exact fp32 recompute for near-tie rows (8 units/wave) ----
    for (int ui = 0; ui < 8; ++ui) {
        int u = w * 8 + ui;
        int c = U.ep.cnt[u]; if (c > NCAND) c = NCAND;
        float thr = U.ep.mxs[u] - MARGIN;
        int nf = 0;
        for (int j = 0; j < c; ++j) nf += (U.ep.sc[u][j] >= thr) ? 1 : 0;
        if (nf > 1) {
            size_t t = t0 + u;
            const float* hr = hs + t * DIMK;
            float4 h0 = *(const float4*)(hr + lane * 8);
            float4 h1 = *(const float4*)(hr + lane * 8 + 4);
            float hv[8] = {h0.x, h0.y, h0.z, h0.w, h1.x, h1.y, h1.z, h1.w};
            float best = -1e30f; int bv2 = 1 << 30;
            for (int j = 0; j < c; ++j) {
                if (U.ep.sc[u][j] < thr) continue;
                int v = U.ep.col[u][j];
                int gcol = g * Vn + v;
                const float* wc = W + gcol;
                float p = 0.f;
                #pragma unroll
                for (int i = 0; i < 8; ++i)
                    p = fmaf(hv[i], wc[(size_t)(lane * 8 + i) * GV], p);
                #pragma unroll
                for (int off = 1; off < 64; off <<= 1) p += __shfl_xor(p, off);
                float se = p + bias[gcol] + U.ep.gmv[u][j];
                if (se > best || (se == best && v < bv2)) { best = se; bv2 = v; }
            }
            if (lane == 0) U.ep.bidx[u] = bv2;
        }
    }
    __syncthreads();

    // ---- gather codevectors -> out ----
    for (int ui = 0; ui < 8; ++ui) {
        int u = w * 8 + ui;
        size_t t = t0 + u;
        int b = U.ep.bidx[u];
        const float2* cvr = (const float2*)(cv + ((size_t)(g * Vn + b)) * Dn);
        float2 val = cvr[lane];
        *(float2*)(out + t * (Gn * Dn) + g * Dn + lane * 2) = val;
    }
}

extern "C" void kernel_launch(void* const* d_in, const int* in_sizes, int n_in,
                              void* d_out, int out_size, void* d_ws, size_t ws_size,
                              hipStream_t stream) {
    const float* hs  = (const float*)d_in[0];  // [8,4096,512]
    const float* W   = (const float*)d_in[1];  // [512,640]
    const float* b   = (const float*)d_in[2];  // [640]
    const float* cv  = (const float*)d_in[3];  // [640,128]
    const float* gum = (const float*)d_in[4];  // [65536,320]

    float* out  = (float*)d_out;                      // [32768, 256]
    float* dist = out + (size_t)Tcnt * (Gn * Dn);     // [65536, 320]
    ushort* Wt  = (ushort*)d_ws;                      // [640, 512] bf16 = 640 KB

    prep_wt<<<80, 256, 0, stream>>>(W, Wt);
    fused_vq_kernel<<<(Tcnt / RB) * Gn, 512, 0, stream>>>(hs, Wt, W, b, gum, cv, out, dist);
}

// Round 15
// 106.941 us; speedup vs baseline: 1.6886x; 1.0293x over previous
//
#include <hip/hip_runtime.h>

#define Tcnt 32768      // B*S
#define Gn   2
#define Vn   320
#define Dn   128
#define DIMK 512
#define GV   640        // G*V
#define RB   64         // rows per fused block
#define NCAND 8

typedef __attribute__((ext_vector_type(8))) short bf16x8;
typedef __attribute__((ext_vector_type(4))) ushort u16x4;
typedef __attribute__((ext_vector_type(4))) float f32x4;

__device__ inline ushort f2bf(float x) {
    unsigned u = __float_as_uint(x);
    return (ushort)((u + 0x7fffu + ((u >> 16) & 1u)) >> 16);   // RNE
}

#define AS1(p) ((const __attribute__((address_space(1))) void*)(p))
#define AS3(p) ((__attribute__((address_space(3))) void*)(p))

// ---------------- prep: W [512,640] fp32 -> Wt [640,512] bf16 (transposed) ----------
__global__ __launch_bounds__(256) void prep_wt(
    const float* __restrict__ W, ushort* __restrict__ Wt)
{
    __shared__ ushort Ls[64][72];
    int t = blockIdx.x;                     // 0..79
    int n0 = (t % 10) * 64, k0 = (t / 10) * 64;
    int ln = threadIdx.x & 63, kq = threadIdx.x >> 6;
    #pragma unroll
    for (int kk = 0; kk < 16; ++kk) {
        int k = kq * 16 + kk;
        Ls[k][ln] = f2bf(W[(size_t)(k0 + k) * GV + n0 + ln]);
    }
    __syncthreads();
    #pragma unroll
    for (int nn = 0; nn < 16; ++nn) {
        int n = kq * 16 + nn;
        Wt[(size_t)(n0 + n) * DIMK + k0 + ln] = Ls[ln][n];
    }
}

// ------- fused: GEMM(64x320) + T14 gum-reg-prefetch + softmax/argmax/fixup/gather ----
// R6 structure (512 thr, staged A, Bs gll dbuf, 95.8us measured) + gum prefetch into
// registers during GEMM steps 8..15 (static indexing -> stays in VGPRs, rule #20).
__global__ __launch_bounds__(512, 4) void fused_vq_kernel(
    const float*  __restrict__ hs,    // [T, 512] fp32
    const ushort* __restrict__ Wt,    // [640, 512] bf16 transposed
    const float*  __restrict__ W,     // [512, 640] fp32 (fixup only)
    const float*  __restrict__ bias,  // [640]
    const float*  __restrict__ gum,   // [T*G, 320]
    const float*  __restrict__ cv,    // [640, 128]
    float* __restrict__ out,          // [T, 256]
    float* __restrict__ dist)         // [T*G, 320]
{
    __shared__ ushort As[2][RB * 32];     // 4 KB x2
    __shared__ ushort Bs[2][Vn * 32];     // 20 KB x2
    __shared__ float4 part[RB][2];        // {mxl, sum, mxs, idx} per half
    __shared__ int    s_cnt[RB];
    __shared__ int    s_col[RB][NCAND];
    __shared__ float  s_s[RB][NCAND];
    __shared__ float  s_gm[RB][NCAND];
    __shared__ int    s_bidx[RB];
    __shared__ float  s_mxs[RB];

    const int tid = threadIdx.x, w = tid >> 6, lane = tid & 63;
    const int Q = lane >> 4, c16 = lane & 15;
    const int wm = (w >> 1) * 16, wn = (w & 1) * 160, half = w & 1;

    const int bid = blockIdx.x;
    const int swz = (bid & 7) * 128 + (bid >> 3);   // XCD chunking (1024 % 8 == 0)
    const int g = swz & 1;                          // (t,g0),(t,g1) adjacent on same XCD
    const size_t t0 = (size_t)(swz >> 1) * RB;

    if (tid < RB) s_cnt[tid] = 0;

    // ---- A staging map: thread -> (row, phys 4-float chunk); source pre-swizzled ----
    const int arow_s = tid >> 3, pc = tid & 7;
    const int lq = (pc >> 1) ^ ((arow_s >> 1) & 3);
    const int lc = lq * 2 + (pc & 1);
    const float* asrc = hs + (t0 + arow_s) * DIMK + lc * 4;
    const ushort* wtg = Wt + (size_t)g * Vn * DIMK;

    auto stageB = [&](int buf, int k0) {
        #pragma unroll
        for (int i2 = 0; i2 < 2; ++i2) {
            int s = i2 * 512 + tid;
            int n = s >> 2, pq = s & 3, lqq = pq ^ ((n >> 1) & 3);
            __builtin_amdgcn_global_load_lds(
                AS1(wtg + (size_t)n * DIMK + k0 + lqq * 8),
                AS3(&Bs[buf][s * 8]), 16, 0, 0);
        }
        if (w < 4) {
            int s = 1024 + tid;
            int n = s >> 2, pq = s & 3, lqq = pq ^ ((n >> 1) & 3);
            __builtin_amdgcn_global_load_lds(
                AS1(wtg + (size_t)n * DIMK + k0 + lqq * 8),
                AS3(&Bs[buf][s * 8]), 16, 0, 0);
        }
    };
    auto writeA = [&](int buf, float4 v) {
        u16x4 o;
        o[0] = f2bf(v.x); o[1] = f2bf(v.y); o[2] = f2bf(v.z); o[3] = f2bf(v.w);
        *(u16x4*)&As[buf][tid * 4] = o;
    };

    // ---- prologue: stage step 0, prefetch step 1 into regs ----
    float4 areg0 = *(const float4*)(asrc);
    stageB(0, 0);
    float4 areg1 = *(const float4*)(asrc + 32);
    writeA(0, areg0);
    __syncthreads();

    f32x4 acc[10];
    #pragma unroll
    for (int j = 0; j < 10; ++j) acc[j] = (f32x4){0.f, 0.f, 0.f, 0.f};

    // T14: gum values prefetched into registers during GEMM steps 8..15.
    // gpre[qr*10 + j] = gum[((t0+wm+Q*4+qr)*2+g)*Vn + wn + j*16 + c16]
    float gpre[40];
    const float* gbase = gum + ((t0 + wm + Q * 4) * 2 + g) * Vn + wn + c16;

    // ---- K loop: 16 steps BK=32, dbuf B (gll), depth-2 A reg prefetch ----
    #pragma unroll
    for (int ks = 0; ks < 16; ++ks) {
        if (ks + 2 < 16) {
            if ((ks & 1) == 0) areg0 = *(const float4*)(asrc + (ks + 2) * 32);
            else               areg1 = *(const float4*)(asrc + (ks + 2) * 32);
        }
        if (ks + 1 < 16) stageB((ks + 1) & 1, (ks + 1) * 32);

        if (ks >= 8) {                 // issue 5 gum loads/step, fully static indices
            const int qq = (ks - 8) >> 1;
            const int jb = ((ks - 8) & 1) * 5;
            const float* grq = gbase + (size_t)qq * 2 * Vn;
            #pragma unroll
            for (int jj = 0; jj < 5; ++jj)
                gpre[qq * 10 + jb + jj] = grq[(jb + jj) * 16];
        }

        const ushort* Ab = As[ks & 1];
        const ushort* Bb = Bs[ks & 1];
        const int ar = wm + c16;
        bf16x8 af = *(const bf16x8*)&Ab[(ar * 4 + (Q ^ ((ar >> 1) & 3))) * 8];
        #pragma unroll
        for (int j = 0; j < 10; ++j) {
            int n = wn + j * 16 + c16;
            bf16x8 bv = *(const bf16x8*)&Bb[(n * 4 + (Q ^ ((n >> 1) & 3))) * 8];
            acc[j] = __builtin_amdgcn_mfma_f32_16x16x32_bf16(af, bv, acc[j], 0, 0, 0);
        }
        if (ks + 1 < 16) writeA((ks + 1) & 1, ((ks + 1) & 1) ? areg1 : areg0);
        __syncthreads();
    }

    // ---- bias ----
    #pragma unroll
    for (int j = 0; j < 10; ++j) {
        float bb = bias[g * Vn + wn + j * 16 + c16];
        acc[j][0] += bb; acc[j][1] += bb; acc[j][2] += bb; acc[j][3] += bb;
    }

    const float MARGIN = 0.0625f;

    // ---- phase 1: per-row half-stats + candidate pool (gum from registers) ----
    #pragma unroll
    for (int qr = 0; qr < 4; ++qr) {
        int row = wm + Q * 4 + qr;                 // local row (C/D layout)
        float sv[10];
        float mxl = -1e30f, mxs = -1e30f; int bi = 0;
        #pragma unroll
        for (int j = 0; j < 10; ++j) {
            float lg = acc[j][qr];
            float s = lg + gpre[qr * 10 + j]; sv[j] = s;
            mxl = fmaxf(mxl, lg);
            if (s > mxs) { mxs = s; bi = wn + j * 16 + c16; }
        }
        #pragma unroll
        for (int off = 1; off < 16; off <<= 1) {
            mxl = fmaxf(mxl, __shfl_xor(mxl, off));
            float os = __shfl_xor(mxs, off); int ob = __shfl_xor(bi, off);
            if (os > mxs || (os == mxs && ob < bi)) { mxs = os; bi = ob; }
        }
        float sum = 0.f;
        #pragma unroll
        for (int j = 0; j < 10; ++j) sum += __expf(acc[j][qr] - mxl);
        #pragma unroll
        for (int off = 1; off < 16; off <<= 1) sum += __shfl_xor(sum, off);

        float thr = mxs - MARGIN;
        #pragma unroll
        for (int j = 0; j < 10; ++j) {
            if (sv[j] >= thr) {
                int pos = atomicAdd(&s_cnt[row], 1);
                if (pos < NCAND) {
                    s_col[row][pos] = wn + j * 16 + c16;
                    s_s[row][pos]   = sv[j];
                    s_gm[row][pos]  = gpre[qr * 10 + j];
                }
            }
        }
        if (c16 == 0)
            part[row][half] = (float4){mxl, sum, mxs, __int_as_float(bi)};
    }
    __syncthreads();

    // ---- phase 2: combine halves, write dist, final approx argmax ----
    #pragma unroll
    for (int qr = 0; qr < 4; ++qr) {
        int row = wm + Q * 4 + qr;
        size_t r2 = (t0 + row) * 2 + g;
        float4 mine = part[row][half];
        float4 oth  = part[row][half ^ 1];
        float mxl_f = fmaxf(mine.x, oth.x);
        float sum_f = mine.y * __expf(mine.x - mxl_f) + oth.y * __expf(oth.x - mxl_f);
        float inv = 1.0f / sum_f;
        float* dr = dist + r2 * Vn + wn;
        #pragma unroll
        for (int j = 0; j < 10; ++j)
            dr[j * 16 + c16] = __expf(acc[j][qr] - mxl_f) * inv;
        if (half == 0 && c16 == 0) {
            float ms = mine.z; int mi = __float_as_int(mine.w);
            float os = oth.z;  int oi = __float_as_int(oth.w);
            if (os > ms || (os == ms && oi < mi)) { ms = os; mi = oi; }
            s_mxs[row] = ms; s_bidx[row] = mi;
        }
    }
    __syncthreads();

    // ---- fixup: exact fp32 recompute for near-tie rows (8 units/wave) ----
    for (int ui = 0; ui < 8; ++ui) {
        int u = w * 8 + ui;
        int c = s_cnt[u]; if (c > NCAND) c = NCAND;
        float thr = s_mxs[u] - MARGIN;
        int nf = 0;
        for (int j = 0; j < c; ++j) nf += (s_s[u][j] >= thr) ? 1 : 0;
        if (nf > 1) {
            size_t t = t0 + u;
            const float* hr = hs + t * DIMK;
            float4 h0 = *(const float4*)(hr + lane * 8);
            float4 h1 = *(const float4*)(hr + lane * 8 + 4);
            float hv[8] = {h0.x, h0.y, h0.z, h0.w, h1.x, h1.y, h1.z, h1.w};
            float best = -1e30f; int bv2 = 1 << 30;
            for (int j = 0; j < c; ++j) {
                if (s_s[u][j] < thr) continue;
                int v = s_col[u][j];
                int gcol = g * Vn + v;
                const float* wc = W + gcol;
                float p = 0.f;
                #pragma unroll
                for (int i = 0; i < 8; ++i)
                    p = fmaf(hv[i], wc[(size_t)(lane * 8 + i) * GV], p);
                #pragma unroll
                for (int off = 1; off < 64; off <<= 1) p += __shfl_xor(p, off);
                float se = p + bias[gcol] + s_gm[u][j];
                if (se > best || (se == best && v < bv2)) { best = se; bv2 = v; }
            }
            if (lane == 0) s_bidx[u] = bv2;
        }
    }
    __syncthreads();

    // ---- gather codevectors -> out ----
    for (int ui = 0; ui < 8; ++ui) {
        int u = w * 8 + ui;
        size_t t = t0 + u;
        int b = s_bidx[u];
        const float2* cvr = (const float2*)(cv + ((size_t)(g * Vn + b)) * Dn);
        float2 val = cvr[lane];
        *(float2*)(out + t * (Gn * Dn) + g * Dn + lane * 2) = val;
    }
}

extern "C" void kernel_launch(void* const* d_in, const int* in_sizes, int n_in,
                              void* d_out, int out_size, void* d_ws, size_t ws_size,
                              hipStream_t stream) {
    const float* hs  = (const float*)d_in[0];  // [8,4096,512]
    const float* W   = (const float*)d_in[1];  // [512,640]
    const float* b   = (const float*)d_in[2];  // [640]
    const float* cv  = (const float*)d_in[3];  // [640,128]
    const float* gum = (const float*)d_in[4];  // [65536,320]

    float* out  = (float*)d_out;                      // [32768, 256]
    float* dist = out + (size_t)Tcnt * (Gn * Dn);     // [65536, 320]
    ushort* Wt  = (ushort*)d_ws;                      // [640, 512] bf16 = 640 KB

    prep_wt<<<80, 256, 0, stream>>>(W, Wt);
    fused_vq_kernel<<<(Tcnt / RB) * Gn, 512, 0, stream>>>(hs, Wt, W, b, gum, cv, out, dist);
}

// Round 16
// 103.092 us; speedup vs baseline: 1.7517x; 1.0373x over previous
//
#include <hip/hip_runtime.h>

#define Tcnt 32768      // B*S
#define Gn   2
#define Vn   320
#define Dn   128
#define DIMK 512
#define GV   640        // G*V
#define RB   128        // rows per fused block

typedef __attribute__((ext_vector_type(8))) short bf16x8;
typedef __attribute__((ext_vector_type(4))) ushort u16x4;
typedef __attribute__((ext_vector_type(4))) float f32x4;

__device__ inline ushort f2bf(float x) {
    unsigned u = __float_as_uint(x);
    return (ushort)((u + 0x7fffu + ((u >> 16) & 1u)) >> 16);   // RNE
}

#define AS1(p) ((const __attribute__((address_space(1))) void*)(p))
#define AS3(p) ((__attribute__((address_space(3))) void*)(p))

// ---------------- prep: W [512,640] fp32 -> Wt [640,512] bf16 (transposed) ----------
__global__ __launch_bounds__(256) void prep_wt(
    const float* __restrict__ W, ushort* __restrict__ Wt)
{
    __shared__ ushort Ls[64][72];
    int t = blockIdx.x;                     // 0..79
    int n0 = (t % 10) * 64, k0 = (t / 10) * 64;
    int ln = threadIdx.x & 63, kq = threadIdx.x >> 6;
    #pragma unroll
    for (int kk = 0; kk < 16; ++kk) {
        int k = kq * 16 + kk;
        Ls[k][ln] = f2bf(W[(size_t)(k0 + k) * GV + n0 + ln]);
    }
    __syncthreads();
    #pragma unroll
    for (int nn = 0; nn < 16; ++nn) {
        int n = kq * 16 + nn;
        Wt[(size_t)(n0 + n) * DIMK + k0 + ln] = Ls[ln][n];
    }
}

// ------- fused: R9 mainloop (champion) + col-major-LDS transposed full-row epilogue --
// 1024 thr / 16 waves; wave-tile 16x160. Epilogue: 4 passes x 32 rows via Ls2[320][33]
// (write bank=(col+lrow)%32 ~2-way free; read bank=(lane+r)%32 exactly 2-way free).
// gum/dist/out accesses become fully-coalesced 256B. No atomics, exact ballot fixup.
__global__ __launch_bounds__(1024, 4) void fused_vq_kernel(
    const float*  __restrict__ hs,    // [T, 512] fp32
    const ushort* __restrict__ Wt,    // [640, 512] bf16 transposed
    const float*  __restrict__ W,     // [512, 640] fp32 (fixup only)
    const float*  __restrict__ bias,  // [640]
    const float*  __restrict__ gum,   // [T*G, 320]
    const float*  __restrict__ cv,    // [640, 128]
    float* __restrict__ out,          // [T, 256]
    float* __restrict__ dist)         // [T*G, 320]
{
    union SMem {
        struct { ushort As[2][RB * 32]; ushort Bs[2][Vn * 32]; } gm;  // 16 + 40 KB
        float Ls2[Vn][33];             // 42.2 KB col-major logits (32 rows/pass)
    };
    __shared__ SMem U;

    const int tid = threadIdx.x, w = tid >> 6, lane = tid & 63;
    const int Q = lane >> 4, c16 = lane & 15;
    const int wm = (w >> 1) * 16, wn = (w & 1) * 160;

    const int bid = blockIdx.x;
    const int swz = (bid & 7) * 64 + (bid >> 3);    // XCD chunking (512 % 8 == 0)
    const int g = swz & 1;                          // (t,g0),(t,g1) adjacent on same XCD
    const size_t t0 = (size_t)(swz >> 1) * RB;

    // ---- A staging map: thread -> (row, phys 4-float chunk); source pre-swizzled ----
    const int arow_s = tid >> 3, pc = tid & 7;
    const int lq = (pc >> 1) ^ ((arow_s >> 1) & 3);
    const int lc = lq * 2 + (pc & 1);
    const float* asrc = hs + (t0 + arow_s) * DIMK + lc * 4;
    const ushort* wtg = Wt + (size_t)g * Vn * DIMK;

    auto stageB = [&](int buf, int k0) {
        {
            int s = tid;
            int n = s >> 2, pq = s & 3, lqq = pq ^ ((n >> 1) & 3);
            __builtin_amdgcn_global_load_lds(
                AS1(wtg + (size_t)n * DIMK + k0 + lqq * 8),
                AS3(&U.gm.Bs[buf][s * 8]), 16, 0, 0);
        }
        if (tid < 256) {
            int s = 1024 + tid;
            int n = s >> 2, pq = s & 3, lqq = pq ^ ((n >> 1) & 3);
            __builtin_amdgcn_global_load_lds(
                AS1(wtg + (size_t)n * DIMK + k0 + lqq * 8),
                AS3(&U.gm.Bs[buf][s * 8]), 16, 0, 0);
        }
    };
    auto writeA = [&](int buf, float4 v) {
        u16x4 o;
        o[0] = f2bf(v.x); o[1] = f2bf(v.y); o[2] = f2bf(v.z); o[3] = f2bf(v.w);
        *(u16x4*)&U.gm.As[buf][tid * 4] = o;
    };

    // ---- prologue: stage step 0, prefetch step 1 into regs ----
    float4 areg0 = *(const float4*)(asrc);
    stageB(0, 0);
    float4 areg1 = *(const float4*)(asrc + 32);
    writeA(0, areg0);
    __syncthreads();

    f32x4 acc[10];
    #pragma unroll
    for (int j = 0; j < 10; ++j) acc[j] = (f32x4){0.f, 0.f, 0.f, 0.f};

    // ---- K loop: 16 steps BK=32, dbuf B (gll), depth-2 A reg prefetch (R9 verbatim) --
    #pragma unroll
    for (int ks = 0; ks < 16; ++ks) {
        if (ks + 2 < 16) {
            if ((ks & 1) == 0) areg0 = *(const float4*)(asrc + (ks + 2) * 32);
            else               areg1 = *(const float4*)(asrc + (ks + 2) * 32);
        }
        if (ks + 1 < 16) stageB((ks + 1) & 1, (ks + 1) * 32);

        const ushort* Ab = U.gm.As[ks & 1];
        const ushort* Bb = U.gm.Bs[ks & 1];
        const int ar = wm + c16;
        bf16x8 af = *(const bf16x8*)&Ab[(ar * 4 + (Q ^ ((ar >> 1) & 3))) * 8];
        #pragma unroll
        for (int j = 0; j < 10; ++j) {
            int n = wn + j * 16 + c16;
            bf16x8 bv = *(const bf16x8*)&Bb[(n * 4 + (Q ^ ((n >> 1) & 3))) * 8];
            acc[j] = __builtin_amdgcn_mfma_f32_16x16x32_bf16(af, bv, acc[j], 0, 0, 0);
        }
        if (ks + 1 < 16) writeA((ks + 1) & 1, ((ks + 1) & 1) ? areg1 : areg0);
        __syncthreads();
    }

    // ---- bias (regs only) ----
    #pragma unroll
    for (int j = 0; j < 10; ++j) {
        float bb = bias[g * Vn + wn + j * 16 + c16];
        acc[j][0] += bb; acc[j][1] += bb; acc[j][2] += bb; acc[j][3] += bb;
    }

    const float MARGIN = 0.0625f;

    // ==== epilogue: 4 passes of 32 rows via col-major LDS; full-row waves ====
    #pragma unroll
    for (int grp = 0; grp < 4; ++grp) {
        __syncthreads();               // previous pass fully read (first: gm dead)
        if ((w >> 2) == grp) {
            int lrow = wm - grp * 32 + Q * 4;       // 0,4,8,..,28
            #pragma unroll
            for (int j = 0; j < 10; ++j) {
                int col = wn + j * 16 + c16;
                U.Ls2[col][lrow + 0] = acc[j][0];   // 4 consecutive -> ds_write_b128
                U.Ls2[col][lrow + 1] = acc[j][1];
                U.Ls2[col][lrow + 2] = acc[j][2];
                U.Ls2[col][lrow + 3] = acc[j][3];
            }
        }
        __syncthreads();

        #pragma unroll
        for (int ri = 0; ri < 2; ++ri) {
            int r = w * 2 + ri;                     // 0..31
            size_t trow = t0 + grp * 32 + r;
            size_t r2 = trow * 2 + g;
            const float* gr = gum + r2 * Vn;

            float lg[5], sv[5];
            #pragma unroll
            for (int j = 0; j < 5; ++j) {
                lg[j] = U.Ls2[lane + j * 64][r];
                sv[j] = lg[j] + gr[lane + j * 64];
            }
            float mxl = -1e30f, mxs = -1e30f; int bi = 0;
            #pragma unroll
            for (int j = 0; j < 5; ++j) {
                mxl = fmaxf(mxl, lg[j]);
                if (sv[j] > mxs) { mxs = sv[j]; bi = lane + j * 64; }
            }
            #pragma unroll
            for (int off = 1; off < 64; off <<= 1) {
                mxl = fmaxf(mxl, __shfl_xor(mxl, off));
                float os = __shfl_xor(mxs, off); int ob = __shfl_xor(bi, off);
                if (os > mxs || (os == mxs && ob < bi)) { mxs = os; bi = ob; }
            }
            float ev[5]; float sum = 0.f;
            #pragma unroll
            for (int j = 0; j < 5; ++j) { ev[j] = __expf(lg[j] - mxl); sum += ev[j]; }
            #pragma unroll
            for (int off = 1; off < 64; off <<= 1) sum += __shfl_xor(sum, off);
            float inv = 1.0f / sum;
            float* dr = dist + r2 * Vn;
            #pragma unroll
            for (int j = 0; j < 5; ++j) dr[lane + j * 64] = ev[j] * inv;

            // ---- exact near-tie detection + inline fp32 fixup ----
            float thr = mxs - MARGIN;
            unsigned long long mj[5];
            int cnt = 0;
            #pragma unroll
            for (int j = 0; j < 5; ++j) { mj[j] = __ballot(sv[j] >= thr); cnt += __popcll(mj[j]); }
            if (cnt > 1) {
                const float* hr = hs + trow * DIMK;
                float4 h0 = *(const float4*)(hr + lane * 8);
                float4 h1 = *(const float4*)(hr + lane * 8 + 4);
                float hv[8] = {h0.x, h0.y, h0.z, h0.w, h1.x, h1.y, h1.z, h1.w};
                float best = -1e30f; int bv2 = 1 << 30;
                #pragma unroll
                for (int j = 0; j < 5; ++j) {
                    unsigned long long m = mj[j];
                    while (m) {
                        int ln = __ffsll((long long)m) - 1; m &= m - 1;
                        int v = ln + j * 64;
                        float gmv = __shfl(sv[j] - lg[j], ln);
                        int gcol = g * Vn + v;
                        const float* wc = W + gcol;
                        float p = 0.f;
                        #pragma unroll
                        for (int i = 0; i < 8; ++i)
                            p = fmaf(hv[i], wc[(size_t)(lane * 8 + i) * GV], p);
                        #pragma unroll
                        for (int off = 1; off < 64; off <<= 1) p += __shfl_xor(p, off);
                        float se = p + bias[gcol] + gmv;
                        if (se > best || (se == best && v < bv2)) { best = se; bv2 = v; }
                    }
                }
                bi = bv2;
            }

            // ---- gather codevector -> out (coalesced 256B) ----
            const float2* cvr = (const float2*)(cv + ((size_t)(g * Vn + bi)) * Dn);
            float2 val = cvr[lane];
            *(float2*)(out + trow * (Gn * Dn) + g * Dn + lane * 2) = val;
        }
    }
}

extern "C" void kernel_launch(void* const* d_in, const int* in_sizes, int n_in,
                              void* d_out, int out_size, void* d_ws, size_t ws_size,
                              hipStream_t stream) {
    const float* hs  = (const float*)d_in[0];  // [8,4096,512]
    const float* W   = (const float*)d_in[1];  // [512,640]
    const float* b   = (const float*)d_in[2];  // [640]
    const float* cv  = (const float*)d_in[3];  // [640,128]
    const float* gum = (const float*)d_in[4];  // [65536,320]

    float* out  = (float*)d_out;                      // [32768, 256]
    float* dist = out + (size_t)Tcnt * (Gn * Dn);     // [65536, 320]
    ushort* Wt  = (ushort*)d_ws;                      // [640, 512] bf16 = 640 KB

    prep_wt<<<80, 256, 0, stream>>>(W, Wt);
    fused_vq_kernel<<<(Tcnt / RB) * Gn, 1024, 0, stream>>>(hs, Wt, W, b, gum, cv, out, dist);
}

// Round 17
// 94.490 us; speedup vs baseline: 1.9111x; 1.0910x over previous
//
#include <hip/hip_runtime.h>

#define Tcnt 32768      // B*S
#define Gn   2
#define Vn   320
#define Dn   128
#define DIMK 512
#define GV   640        // G*V
#define RB   64         // rows per fused block
#define NCAND 8

typedef __attribute__((ext_vector_type(8))) short bf16x8;
typedef __attribute__((ext_vector_type(4))) ushort u16x4;
typedef __attribute__((ext_vector_type(4))) float f32x4;

__device__ inline ushort f2bf(float x) {
    unsigned u = __float_as_uint(x);
    return (ushort)((u + 0x7fffu + ((u >> 16) & 1u)) >> 16);   // RNE
}

#define AS1(p) ((const __attribute__((address_space(1))) void*)(p))
#define AS3(p) ((__attribute__((address_space(3))) void*)(p))

// ---------------- prep: W [512,640] fp32 -> Wt [640,512] bf16 (transposed) ----------
__global__ __launch_bounds__(256) void prep_wt(
    const float* __restrict__ W, ushort* __restrict__ Wt)
{
    __shared__ ushort Ls[64][72];
    int t = blockIdx.x;                     // 0..79
    int n0 = (t % 10) * 64, k0 = (t / 10) * 64;
    int ln = threadIdx.x & 63, kq = threadIdx.x >> 6;
    #pragma unroll
    for (int kk = 0; kk < 16; ++kk) {
        int k = kq * 16 + kk;
        Ls[k][ln] = f2bf(W[(size_t)(k0 + k) * GV + n0 + ln]);
    }
    __syncthreads();
    #pragma unroll
    for (int nn = 0; nn < 16; ++nn) {
        int n = kq * 16 + nn;
        Wt[(size_t)(n0 + n) * DIMK + k0 + ln] = Ls[ln][n];
    }
}

// ------- fused: R6 structure (512 thr, staged A, 95.8us proven) + LDS union ---------
// LDS = union(gm 48K, ep 8.8K) = 48KB -> 3 blocks/CU (R6 had 58.4K -> 2 blocks/CU).
// Grid 1024 -> multiple block-rounds per CU: next round's GEMM overlaps this round's
// epilogue. Mainloop + epilogue logic verbatim from R6; only s_cnt init moved post-GEMM.
__global__ __launch_bounds__(512, 4) void fused_vq_kernel(
    const float*  __restrict__ hs,    // [T, 512] fp32
    const ushort* __restrict__ Wt,    // [640, 512] bf16 transposed
    const float*  __restrict__ W,     // [512, 640] fp32 (fixup only)
    const float*  __restrict__ bias,  // [640]
    const float*  __restrict__ gum,   // [T*G, 320]
    const float*  __restrict__ cv,    // [640, 128]
    float* __restrict__ out,          // [T, 256]
    float* __restrict__ dist)         // [T*G, 320]
{
    union SMem {
        struct { ushort As[2][RB * 32]; ushort Bs[2][Vn * 32]; } gm;  // 8 + 40 KB
        struct {
            float4 part[RB][2];       // {mxl, sum, mxs, idx} per col-half
            int    cnt[RB];
            int    col[RB][NCAND];
            float  sc[RB][NCAND];
            float  gmv[RB][NCAND];
            int    bidx[RB];
            float  mxs[RB];
        } ep;                          // ~8.8 KB
    };
    __shared__ SMem U;

    const int tid = threadIdx.x, w = tid >> 6, lane = tid & 63;
    const int Q = lane >> 4, c16 = lane & 15;
    const int wm = (w >> 1) * 16, wn = (w & 1) * 160, half = w & 1;

    const int bid = blockIdx.x;
    const int swz = (bid & 7) * 128 + (bid >> 3);   // XCD chunking (1024 % 8 == 0)
    const int g = swz & 1;                          // (t,g0),(t,g1) adjacent on same XCD
    const size_t t0 = (size_t)(swz >> 1) * RB;

    // ---- A staging map: thread -> (row, phys 4-float chunk); source pre-swizzled ----
    const int arow_s = tid >> 3, pc = tid & 7;
    const int lq = (pc >> 1) ^ ((arow_s >> 1) & 3);
    const int lc = lq * 2 + (pc & 1);
    const float* asrc = hs + (t0 + arow_s) * DIMK + lc * 4;
    const ushort* wtg = Wt + (size_t)g * Vn * DIMK;

    auto stageB = [&](int buf, int k0) {
        #pragma unroll
        for (int i2 = 0; i2 < 2; ++i2) {
            int s = i2 * 512 + tid;
            int n = s >> 2, pq = s & 3, lqq = pq ^ ((n >> 1) & 3);
            __builtin_amdgcn_global_load_lds(
                AS1(wtg + (size_t)n * DIMK + k0 + lqq * 8),
                AS3(&U.gm.Bs[buf][s * 8]), 16, 0, 0);
        }
        if (w < 4) {
            int s = 1024 + tid;
            int n = s >> 2, pq = s & 3, lqq = pq ^ ((n >> 1) & 3);
            __builtin_amdgcn_global_load_lds(
                AS1(wtg + (size_t)n * DIMK + k0 + lqq * 8),
                AS3(&U.gm.Bs[buf][s * 8]), 16, 0, 0);
        }
    };
    auto writeA = [&](int buf, float4 v) {
        u16x4 o;
        o[0] = f2bf(v.x); o[1] = f2bf(v.y); o[2] = f2bf(v.z); o[3] = f2bf(v.w);
        *(u16x4*)&U.gm.As[buf][tid * 4] = o;
    };

    // ---- prologue: stage step 0, prefetch step 1 into regs ----
    float4 areg0 = *(const float4*)(asrc);
    stageB(0, 0);
    float4 areg1 = *(const float4*)(asrc + 32);
    writeA(0, areg0);
    __syncthreads();

    f32x4 acc[10];
    #pragma unroll
    for (int j = 0; j < 10; ++j) acc[j] = (f32x4){0.f, 0.f, 0.f, 0.f};

    // ---- K loop: 16 steps BK=32, dbuf B (gll), depth-2 A reg prefetch ----
    #pragma unroll
    for (int ks = 0; ks < 16; ++ks) {
        if (ks + 2 < 16) {
            if ((ks & 1) == 0) areg0 = *(const float4*)(asrc + (ks + 2) * 32);
            else               areg1 = *(const float4*)(asrc + (ks + 2) * 32);
        }
        if (ks + 1 < 16) stageB((ks + 1) & 1, (ks + 1) * 32);

        const ushort* Ab = U.gm.As[ks & 1];
        const ushort* Bb = U.gm.Bs[ks & 1];
        const int ar = wm + c16;
        bf16x8 af = *(const bf16x8*)&Ab[(ar * 4 + (Q ^ ((ar >> 1) & 3))) * 8];
        #pragma unroll
        for (int j = 0; j < 10; ++j) {
            int n = wn + j * 16 + c16;
            bf16x8 bv = *(const bf16x8*)&Bb[(n * 4 + (Q ^ ((n >> 1) & 3))) * 8];
            acc[j] = __builtin_amdgcn_mfma_f32_16x16x32_bf16(af, bv, acc[j], 0, 0, 0);
        }
        if (ks + 1 < 16) writeA((ks + 1) & 1, ((ks + 1) & 1) ? areg1 : areg0);
        __syncthreads();
    }
    // gm staging LDS now dead; ep union used after next barrier.

    // ---- bias ----
    #pragma unroll
    for (int j = 0; j < 10; ++j) {
        float bb = bias[g * Vn + wn + j * 16 + c16];
        acc[j][0] += bb; acc[j][1] += bb; acc[j][2] += bb; acc[j][3] += bb;
    }

    if (tid < RB) U.ep.cnt[tid] = 0;
    __syncthreads();

    const float MARGIN = 0.0625f;

    // ---- phase 1: per-row half-stats + candidate pool ----
    #pragma unroll
    for (int qr = 0; qr < 4; ++qr) {
        int row = wm + Q * 4 + qr;                 // local row (C/D layout)
        size_t r2 = (t0 + row) * 2 + g;
        const float* gr = gum + r2 * Vn + wn;
        float sv[10];
        float mxl = -1e30f, mxs = -1e30f; int bi = 0;
        #pragma unroll
        for (int j = 0; j < 10; ++j) {
            float lg = acc[j][qr];
            float gu = gr[j * 16 + c16];
            float s = lg + gu; sv[j] = s;
            mxl = fmaxf(mxl, lg);
            if (s > mxs) { mxs = s; bi = wn + j * 16 + c16; }
        }
        #pragma unroll
        for (int off = 1; off < 16; off <<= 1) {
            mxl = fmaxf(mxl, __shfl_xor(mxl, off));
            float os = __shfl_xor(mxs, off); int ob = __shfl_xor(bi, off);
            if (os > mxs || (os == mxs && ob < bi)) { mxs = os; bi = ob; }
        }
        float sum = 0.f;
        #pragma unroll
        for (int j = 0; j < 10; ++j) sum += __expf(acc[j][qr] - mxl);
        #pragma unroll
        for (int off = 1; off < 16; off <<= 1) sum += __shfl_xor(sum, off);

        float thr = mxs - MARGIN;
        #pragma unroll
        for (int j = 0; j < 10; ++j) {
            if (sv[j] >= thr) {
                int pos = atomicAdd(&U.ep.cnt[row], 1);
                if (pos < NCAND) {
                    U.ep.col[row][pos] = wn + j * 16 + c16;
                    U.ep.sc[row][pos]  = sv[j];
                    U.ep.gmv[row][pos] = sv[j] - acc[j][qr];
                }
            }
        }
        if (c16 == 0)
            U.ep.part[row][half] = (float4){mxl, sum, mxs, __int_as_float(bi)};
    }
    __syncthreads();

    // ---- phase 2: combine halves, write dist, final approx argmax ----
    #pragma unroll
    for (int qr = 0; qr < 4; ++qr) {
        int row = wm + Q * 4 + qr;
        size_t r2 = (t0 + row) * 2 + g;
        float4 mine = U.ep.part[row][half];
        float4 oth  = U.ep.part[row][half ^ 1];
        float mxl_f = fmaxf(mine.x, oth.x);
        float sum_f = mine.y * __expf(mine.x - mxl_f) + oth.y * __expf(oth.x - mxl_f);
        float inv = 1.0f / sum_f;
        float* dr = dist + r2 * Vn + wn;
        #pragma unroll
        for (int j = 0; j < 10; ++j)
            dr[j * 16 + c16] = __expf(acc[j][qr] - mxl_f) * inv;
        if (half == 0 && c16 == 0) {
            float ms = mine.z; int mi = __float_as_int(mine.w);
            float os = oth.z;  int oi = __float_as_int(oth.w);
            if (os > ms || (os == ms && oi < mi)) { ms = os; mi = oi; }
            U.ep.mxs[row] = ms; U.ep.bidx[row] = mi;
        }
    }
    __syncthreads();

    // ---- fixup: exact fp32 recompute for near-tie rows (8 units/wave) ----
    for (int ui = 0; ui < 8; ++ui) {
        int u = w * 8 + ui;
        int c = U.ep.cnt[u]; if (c > NCAND) c = NCAND;
        float thr = U.ep.mxs[u] - MARGIN;
        int nf = 0;
        for (int j = 0; j < c; ++j) nf += (U.ep.sc[u][j] >= thr) ? 1 : 0;
        if (nf > 1) {
            size_t t = t0 + u;
            const float* hr = hs + t * DIMK;
            float4 h0 = *(const float4*)(hr + lane * 8);
            float4 h1 = *(const float4*)(hr + lane * 8 + 4);
            float hv[8] = {h0.x, h0.y, h0.z, h0.w, h1.x, h1.y, h1.z, h1.w};
            float best = -1e30f; int bv2 = 1 << 30;
            for (int j = 0; j < c; ++j) {
                if (U.ep.sc[u][j] < thr) continue;
                int v = U.ep.col[u][j];
                int gcol = g * Vn + v;
                const float* wc = W + gcol;
                float p = 0.f;
                #pragma unroll
                for (int i = 0; i < 8; ++i)
                    p = fmaf(hv[i], wc[(size_t)(lane * 8 + i) * GV], p);
                #pragma unroll
                for (int off = 1; off < 64; off <<= 1) p += __shfl_xor(p, off);
                float se = p + bias[gcol] + U.ep.gmv[u][j];
                if (se > best || (se == best && v < bv2)) { best = se; bv2 = v; }
            }
            if (lane == 0) U.ep.bidx[u] = bv2;
        }
    }
    __syncthreads();

    // ---- gather codevectors -> out ----
    for (int ui = 0; ui < 8; ++ui) {
        int u = w * 8 + ui;
        size_t t = t0 + u;
        int b = U.ep.bidx[u];
        const float2* cvr = (const float2*)(cv + ((size_t)(g * Vn + b)) * Dn);
        float2 val = cvr[lane];
        *(float2*)(out + t * (Gn * Dn) + g * Dn + lane * 2) = val;
    }
}

extern "C" void kernel_launch(void* const* d_in, const int* in_sizes, int n_in,
                              void* d_out, int out_size, void* d_ws, size_t ws_size,
                              hipStream_t stream) {
    const float* hs  = (const float*)d_in[0];  // [8,4096,512]
    const float* W   = (const float*)d_in[1];  // [512,640]
    const float* b   = (const float*)d_in[2];  // [640]
    const float* cv  = (const float*)d_in[3];  // [640,128]
    const float* gum = (const float*)d_in[4];  // [65536,320]

    float* out  = (float*)d_out;                      // [32768, 256]
    float* dist = out + (size_t)Tcnt * (Gn * Dn);     // [65536, 320]
    ushort* Wt  = (ushort*)d_ws;                      // [640, 512] bf16 = 640 KB

    prep_wt<<<80, 256, 0, stream>>>(W, Wt);
    fused_vq_kernel<<<(Tcnt / RB) * Gn, 512, 0, stream>>>(hs, Wt, W, b, gum, cv, out, dist);
}